// Round 8
// baseline (272.359 us; speedup 1.0000x reference)
//
#include <hip/hip_runtime.h>

#define SQ3F 0.35355339059327379f

__device__ __forceinline__ float rfl(float v) {
    return __int_as_float(__builtin_amdgcn_readfirstlane(__float_as_int(v)));
}

// Forward 2x2x2 Haar butterfly. v index = z*4+y*2+x. o index = fz*4+fy*2+fx.
__device__ __forceinline__ void haar_fwd(const float v[8], float o[8]) {
    float ax[8];
#pragma unroll
    for (int i = 0; i < 4; ++i) {
        float a = v[2 * i], b = v[2 * i + 1];
        ax[2 * i]     = a + b;
        ax[2 * i + 1] = b - a;
    }
    float ay[8];
#pragma unroll
    for (int z = 0; z < 2; ++z)
#pragma unroll
        for (int bx = 0; bx < 2; ++bx) {
            float a = ax[z * 4 + bx], b = ax[z * 4 + 2 + bx];
            ay[z * 4 + bx]     = a + b;
            ay[z * 4 + 2 + bx] = b - a;
        }
#pragma unroll
    for (int j = 0; j < 4; ++j) {
        float a = ay[j], b = ay[4 + j];
        o[j]     = (a + b) * SQ3F;
        o[4 + j] = (b - a) * SQ3F;
    }
}

// Inverse Haar. t index = fz*4+fy*2+fx. o index = z*4+y*2+x.
__device__ __forceinline__ void haar_inv(const float t[8], float o[8]) {
    float az[8];
#pragma unroll
    for (int j = 0; j < 4; ++j) {
        float lo = t[j], hi = t[4 + j];
        az[j]     = lo + hi;
        az[4 + j] = lo - hi;
    }
    float ay[8];
#pragma unroll
    for (int z = 0; z < 2; ++z)
#pragma unroll
        for (int bx = 0; bx < 2; ++bx) {
            float lo = az[z * 4 + bx], hi = az[z * 4 + 2 + bx];
            ay[z * 4 + bx]     = lo + hi;
            ay[z * 4 + 2 + bx] = lo - hi;
        }
#pragma unroll
    for (int i = 0; i < 4; ++i) {
        float lo = ay[2 * i], hi = ay[2 * i + 1];
        o[2 * i]     = (lo + hi) * SQ3F;
        o[2 * i + 1] = (lo - hi) * SQ3F;
    }
}

// ============ Fused level-0: DWT + depthwise conv + soft-threshold =========
// R8: R6 + T14 prefetch done right (R3's confound removed: float4 staging
// loads kept verbatim). Single 4xfloat4 prefetch buffer; per phase the next
// plane's loads are issued right after the current buffer is consumed, so
// they fly across LDS-write + barrier + fold + finalize (>1000 cyc).
__global__ __launch_bounds__(512, 6) void fused_l0_k(
    const float* __restrict__ x, const float* __restrict__ wt,
    const float* __restrict__ wscale, const float* __restrict__ lambd_p,
    float* __restrict__ t0, float* __restrict__ cx1) {
    __shared__ __align__(16) float pl[8][32][36];
    int bx   = ((blockIdx.x & 7) << 7) + (blockIdx.x >> 3);  // XCD-chunked
    int slab = bx & 15;
    int c    = bx >> 4;
    int z0   = slab * 2;
    int tid  = threadIdx.x;

    // zero the x-pad columns once (512 pad slots, one per thread)
    {
        int fi   = tid >> 6;
        int rowi = (tid >> 1) & 31;
        pl[fi][rowi][(tid & 1) * 33] = 0.f;
    }

    int f    = __builtin_amdgcn_readfirstlane(tid >> 6);  // band, wave-uniform
    int lane = tid & 63;
    int cty  = lane >> 1;         // conv row 0..31
    int cx0i = (lane & 1) * 16;   // 16-wide x chunk
    int cc   = c * 8 + f;         // wave-uniform
    float wv[27];
    const float* wp = wt + cc * 27;
#pragma unroll
    for (int k = 0; k < 27; ++k) wv[k] = rfl(wp[k]);  // SGPRs
    float lam = rfl(*lambd_p);
    float sc  = rfl(wscale[cc]);

    const float* xc = x + ((long)c << 18);

    // staging cell geometry (2 x-adjacent cells per thread)
    int cell = 2 * tid;
    int y    = cell >> 5;
    int xx   = cell & 31;  // even

    float4 pre[4];  // prefetch buffer: pre[z*2+yy]
    auto issue_loads = [&](int p) {
#pragma unroll
        for (int z = 0; z < 2; ++z)
#pragma unroll
            for (int yy = 0; yy < 2; ++yy)
                pre[z * 2 + yy] = *(const float4*)(
                    xc + (((2 * p + z) << 6) + (2 * y + yy)) * 64 + 2 * xx);
    };

    float acc[2][16];
#pragma unroll
    for (int s = 0; s < 2; ++s)
#pragma unroll
        for (int j = 0; j < 16; ++j) acc[s][j] = 0.f;

    float llq00 = 0.f, llq01 = 0.f;  // raw LL of plane z0 (this thread's 2 cells)

    // prologue: issue loads for the first folded plane
    if (z0 - 1 >= 0) issue_loads(z0 - 1);

    // pp fully unrolled so acc/ring indices are compile-time constants.
#pragma unroll
    for (int pp = 0; pp < 4; ++pp) {
        int p       = z0 - 1 + pp;
        bool pvalid = (p >= 0) && (p <= 31);  // wave-uniform
        int pn      = p + 1;
        bool pnv    = (pp < 3) && (pn <= 31); // wave-uniform
        __syncthreads();
        float v0[8], v1[8];
        if (pvalid) {
            // consume prefetch buffer into locals
#pragma unroll
            for (int z = 0; z < 2; ++z)
#pragma unroll
                for (int yy = 0; yy < 2; ++yy) {
                    float4 q = pre[z * 2 + yy];
                    v0[z * 4 + yy * 2]     = q.x;
                    v0[z * 4 + yy * 2 + 1] = q.y;
                    v1[z * 4 + yy * 2]     = q.z;
                    v1[z * 4 + yy * 2 + 1] = q.w;
                }
        }
        if (pnv) issue_loads(pn);  // in flight across LDS-write+barrier+fold
        if (pvalid) {
            float o0[8], o1[8];
            haar_fwd(v0, o0);
            haar_fwd(v1, o1);
#pragma unroll
            for (int k = 0; k < 8; ++k) {
                pl[k][y][xx + 1] = o0[k];
                pl[k][y][xx + 2] = o1[k];
            }
            if (pp == 1) {  // plane z0: stash raw LL for level-1 DWT
                llq00 = o0[0];
                llq01 = o1[0];
            }
            if (pp == 2) {  // plane z0+1: complete the level-1 cell, write cx1
                float l10 = o0[0], l11 = o1[0];
                // y-parity partner = lane^16 (same wave; pvalid wave-uniform)
                float p00 = __shfl_xor(llq00, 16);
                float p01 = __shfl_xor(llq01, 16);
                float p10 = __shfl_xor(l10, 16);
                float p11 = __shfl_xor(l11, 16);
                int yp = (tid >> 4) & 1;  // y parity
                float v[8];  // v[z*4 + yy*2 + xp]
                if (yp == 0) {
                    v[0] = llq00; v[1] = llq01; v[2] = p00; v[3] = p01;
                    v[4] = l10;   v[5] = l11;   v[6] = p10; v[7] = p11;
                } else {
                    v[0] = p00;   v[1] = p01;   v[2] = llq00; v[3] = llq01;
                    v[4] = p10;   v[5] = p11;   v[6] = l10;   v[7] = l11;
                }
                float o[8];
                haar_fwd(v, o);
                int d  = z0 >> 1;
                int hy = (tid >> 4) >> 1;   // y/2, 0..15
                int wx = tid & 15;          // xx/2
                int sA = (d * 16 + hy) * 16 + wx;
                int f0 = yp * 4;  // even-y writes bands 0-3, odd-y bands 4-7
#pragma unroll
                for (int q = 0; q < 4; ++q)
                    cx1[((c * 8 + f0 + q) << 12) + sA] = o[f0 + q];
            }
        }
        __syncthreads();
        if (pvalid) {
            // fold plane p into pending outputs zc = p+1-dz (rel = pp-dz)
#pragma unroll
            for (int dy = 0; dy < 3; ++dy) {
                int yy = cty - 1 + dy;
                if ((unsigned)yy < 32u) {
                    float r[18];
                    {
                        const float* rp = &pl[f][yy][cx0i];
                        float4 a0 = *(const float4*)(rp);
                        float4 a1 = *(const float4*)(rp + 4);
                        float4 a2 = *(const float4*)(rp + 8);
                        float4 a3 = *(const float4*)(rp + 12);
                        float2 a4 = *(const float2*)(rp + 16);
                        r[0]  = a0.x; r[1]  = a0.y; r[2]  = a0.z; r[3]  = a0.w;
                        r[4]  = a1.x; r[5]  = a1.y; r[6]  = a1.z; r[7]  = a1.w;
                        r[8]  = a2.x; r[9]  = a2.y; r[10] = a2.z; r[11] = a2.w;
                        r[12] = a3.x; r[13] = a3.y; r[14] = a3.z; r[15] = a3.w;
                        r[16] = a4.x; r[17] = a4.y;
                    }
#pragma unroll
                    for (int dz = 0; dz < 3; ++dz) {
                        int rel = pp - dz;
                        if (rel >= 0 && rel <= 1) {  // compile-time
#pragma unroll
                            for (int dx = 0; dx < 3; ++dx) {
                                float wgt = wv[dz * 9 + dy * 3 + dx];
#pragma unroll
                                for (int j = 0; j < 16; ++j)
                                    acc[rel][j] += r[dx + j] * wgt;
                            }
                        }
                    }
                }
            }
        }
        // finalize output zc = z0+rel (rel = pp-2) — needs planes zc-1..zc+1
        {
            int rel = pp - 2;
            if (rel >= 0 && rel <= 1) {  // compile-time
                int zc = z0 + rel;
                float res[16];
#pragma unroll
                for (int j = 0; j < 16; ++j) {
                    float t = acc[rel][j];
                    if (f != 0) {
                        float a = fabsf(t) - lam;
                        t       = a > 0.f ? copysignf(a, t) : 0.f;
                    }
                    res[j]      = t * sc;
                    acc[rel][j] = 0.f;
                }
                float* op = t0 + ((long)cc << 15) + (zc << 10) + cty * 32 + cx0i;
#pragma unroll
                for (int q = 0; q < 4; ++q)
                    *(float4*)(op + q * 4) = float4{res[q * 4], res[q * 4 + 1],
                                                    res[q * 4 + 2], res[q * 4 + 3]};
            }
        }
    }
}

// ===================== Level-1 conv kernel (R7 pipeline) =====================
template <int S, int SLOT>
__device__ __forceinline__ void load_plane4(const float* __restrict__ ip,
                                            int z, int ty, int x0,
                                            float win[4][3][6]) {
    bool zok = ((unsigned)z < (unsigned)S);
    const float* pp = ip + z * S * S;
#pragma unroll
    for (int dy = 0; dy < 3; ++dy) {
        int yy  = ty - 1 + dy;
        bool yok = zok && ((unsigned)yy < (unsigned)S);
        const float* rp = pp + yy * S;
        win[SLOT][dy][0] = (yok && x0 > 0) ? rp[x0 - 1] : 0.f;
        float4 m = yok ? *(const float4*)(rp + x0) : float4{0.f, 0.f, 0.f, 0.f};
        win[SLOT][dy][1] = m.x;
        win[SLOT][dy][2] = m.y;
        win[SLOT][dy][3] = m.z;
        win[SLOT][dy][4] = m.w;
        win[SLOT][dy][5] = (yok && (x0 + 4 < S)) ? rp[x0 + 4] : 0.f;
    }
}

template <int S, int SP, int SC, int SN>
__device__ __forceinline__ void conv_compute(int zo, int ty, int x0,
                                             const float* __restrict__ wv,
                                             const float win[4][3][6], float lam,
                                             float sc, bool hf,
                                             float* __restrict__ op) {
    float acc[4] = {0.f, 0.f, 0.f, 0.f};
#pragma unroll
    for (int dz = 0; dz < 3; ++dz) {
        const float(*wp)[6] = (dz == 0) ? win[SP] : (dz == 1) ? win[SC] : win[SN];
#pragma unroll
        for (int dy = 0; dy < 3; ++dy)
#pragma unroll
            for (int dx = 0; dx < 3; ++dx) {
                float wgt = wv[dz * 9 + dy * 3 + dx];
#pragma unroll
                for (int j = 0; j < 4; ++j) acc[j] += wp[dy][dx + j] * wgt;
            }
    }
    float4 r;
    float* rr = (float*)&r;
#pragma unroll
    for (int j = 0; j < 4; ++j) {
        float t = acc[j];
        if (hf) {
            float a = fabsf(t) - lam;
            t       = a > 0.f ? copysignf(a, t) : 0.f;
        }
        rr[j] = t * sc;
    }
    *(float4*)(op + (zo * S + ty) * S + x0) = r;
}

// z split into 4 chunks of 4 -> grid 512 blocks; XCD-chunked swizzle.
template <int S, int CPB>
__global__ __launch_bounds__(256) void dwconv_soft_pipe_k(
    const float* __restrict__ in, const float* __restrict__ wt,
    const float* __restrict__ wscale, const float* __restrict__ lambd_p,
    float* __restrict__ out) {
    constexpr int TX = S / 4;
    int bxl = ((blockIdx.x & 7) << 6) + (blockIdx.x >> 3);  // XCD-chunked
    int tid = threadIdx.x;
    int tx  = tid % TX;
    int ty  = (tid / TX) % S;
    int cs  = tid / (TX * S);
    int zc  = bxl & 3;
    int cg  = bxl >> 2;
    int cc  = cg * CPB + cs;
    const float* ip = in + (long)cc * (S * S * S);
    float* op       = out + (long)cc * (S * S * S);
    float wv[27];
#pragma unroll
    for (int k = 0; k < 27; ++k) wv[k] = wt[cc * 27 + k];
    float lam = *lambd_p;
    float sc  = wscale[cc];
    bool hf   = (cc & 7) != 0;
    int x0    = 4 * tx;
    int z0    = 4 * zc;  // multiple of 4 -> slot = plane & 3

    float win[4][3][6];
    load_plane4<S, 3>(ip, z0 - 1, ty, x0, win);  // (-1)&3 == 3
    load_plane4<S, 0>(ip, z0,     ty, x0, win);
    load_plane4<S, 1>(ip, z0 + 1, ty, x0, win);
    load_plane4<S, 2>(ip, z0 + 2, ty, x0, win);
    conv_compute<S, 3, 0, 1>(z0, ty, x0, wv, win, lam, sc, hf, op);
    load_plane4<S, 3>(ip, z0 + 3, ty, x0, win);
    conv_compute<S, 0, 1, 2>(z0 + 1, ty, x0, wv, win, lam, sc, hf, op);
    load_plane4<S, 0>(ip, z0 + 4, ty, x0, win);
    conv_compute<S, 1, 2, 3>(z0 + 2, ty, x0, wv, win, lam, sc, hf, op);
    conv_compute<S, 2, 3, 0>(z0 + 3, ty, x0, wv, win, lam, sc, hf, op);
}

// ========== Final: LDS-tiled base conv + level-1 idwt + level-0 idwt =======
// FROZEN (R7 form): tile/mapping/epilogue-hoist validated. 79 µs, traffic
// near-ideal (FETCH 79 MB / WRITE 70 MB).
__global__ __launch_bounds__(256, 3) void final_k2(
    const float* __restrict__ x, const float* __restrict__ t0,
    const float* __restrict__ t1, const float* __restrict__ bw,
    const float* __restrict__ bb, const float* __restrict__ bscale,
    float* __restrict__ out) {
    __shared__ float xs[18 * 10 * 67];
    int bx = blockIdx.x;
    int c  = bx >> 5;
    int ti = bx & 31;
    int dt = ti >> 3;  // z tile (16 thick)
    int ht = ti & 7;   // y tile (8 thick)
    const float* xc = x + ((long)c << 18);

    int tid = threadIdx.x;
    int wc  = tid & 7;         // x chunk: cells w0..w0+3
    int hc  = (tid >> 3) & 3;  // h cell in tile
    int dc  = tid >> 5;        // d cell in tile
    int d   = dt * 8 + dc;
    int h   = ht * 4 + hc;
    int w0  = wc * 4;

    // ---- epilogue data: issue loads FIRST (independent of xs) ----
    int cell0 = (d << 10) + (h << 5) + w0;
    float4 t0v[8];
#pragma unroll
    for (int f = 0; f < 8; ++f)
        t0v[f] = *(const float4*)(t0 + (((long)(c * 8 + f)) << 15) + cell0);
    int s1b = ((d >> 1) * 16 + (h >> 1)) * 16 + (w0 >> 1);
    float2 t1v[8];
#pragma unroll
    for (int f = 0; f < 8; ++f)
        t1v[f] = *(const float2*)(t1 + ((c * 8 + f) << 12) + s1b);

    // ---- stage x tile ----
    int zg0 = 16 * dt - 1, yg0 = 8 * ht - 1;
    for (int i = tid; i < 18 * 10 * 66; i += 256) {
        int pz = i / 660;
        int r  = i - pz * 660;
        int py = r / 66;
        int px = r - py * 66;
        int zg = zg0 + pz, yg = yg0 + py, xg = px - 1;
        bool ok = ((unsigned)zg < 64u) && ((unsigned)yg < 64u) && ((unsigned)xg < 64u);
        xs[(pz * 10 + py) * 67 + px] = ok ? xc[(zg << 12) + (yg << 6) + xg] : 0.f;
    }
    const float* wp0 = bw + c * 27;
    float wv[27];
#pragma unroll
    for (int k = 0; k < 27; ++k) wv[k] = wp0[k];
    float bias = bb[c], scl = bscale[c];
    __syncthreads();

    float acc[2][2][8];
#pragma unroll
    for (int oz = 0; oz < 2; ++oz)
#pragma unroll
        for (int oy = 0; oy < 2; ++oy)
#pragma unroll
            for (int m = 0; m < 8; ++m) acc[oz][oy][m] = 0.f;

#pragma unroll
    for (int pz = 0; pz < 4; ++pz) {
        float r[4][10];
#pragma unroll
        for (int py = 0; py < 4; ++py)
#pragma unroll
            for (int k = 0; k < 10; ++k)
                r[py][k] = xs[((2 * dc + pz) * 10 + (2 * hc + py)) * 67 + 8 * wc + k];
#pragma unroll
        for (int oz = 0; oz < 2; ++oz) {
            int kz = pz - oz;
            if (kz >= 0 && kz <= 2) {
#pragma unroll
                for (int py = 0; py < 4; ++py)
#pragma unroll
                    for (int oy = 0; oy < 2; ++oy) {
                        int ky = py - oy;
                        if (ky >= 0 && ky <= 2) {
#pragma unroll
                            for (int kx = 0; kx < 3; ++kx) {
                                float wgt = wv[kz * 9 + ky * 3 + kx];
#pragma unroll
                                for (int m = 0; m < 8; ++m)
                                    acc[oz][oy][m] += r[py][m + kx] * wgt;
                            }
                        }
                    }
            }
        }
    }

    // epilogue: t0/t1 already in registers; idwt + store
#pragma unroll
    for (int j = 0; j < 4; ++j) {
        int w = w0 + j;
        float tf[8];
#pragma unroll
        for (int f = 0; f < 8; ++f) tf[f] = ((const float*)&t0v[f])[j];
        float add = 0.f;
#pragma unroll
        for (int f = 0; f < 8; ++f) {
            float v  = (j >> 1) ? t1v[f].y : t1v[f].x;
            float sg = 1.f;
            if ((f & 4) && (d & 1)) sg = -sg;
            if ((f & 2) && (h & 1)) sg = -sg;
            if ((f & 1) && (j & 1)) sg = -sg;
            add += sg * v;
        }
        tf[0] += add * SQ3F;
        float contrib[8];
        haar_inv(tf, contrib);
#pragma unroll
        for (int oz = 0; oz < 2; ++oz)
#pragma unroll
            for (int oy = 0; oy < 2; ++oy) {
                float2 rr;
                rr.x = (acc[oz][oy][2 * j] + bias) * scl + contrib[oz * 4 + oy * 2];
                rr.y = (acc[oz][oy][2 * j + 1] + bias) * scl +
                       contrib[oz * 4 + oy * 2 + 1];
                *(float2*)(out + ((long)c << 18) + ((2 * d + oz) << 12) +
                           ((2 * h + oy) << 6) + 2 * w) = rr;
            }
    }
}

extern "C" void kernel_launch(void* const* d_in, const int* in_sizes, int n_in,
                              void* d_out, int out_size, void* d_ws, size_t ws_size,
                              hipStream_t stream) {
    const float* x      = (const float*)d_in[0];
    const float* base_w = (const float*)d_in[1];
    const float* base_b = (const float*)d_in[2];
    const float* base_s = (const float*)d_in[3];
    const float* w0     = (const float*)d_in[4];
    const float* w1     = (const float*)d_in[5];
    const float* ws0    = (const float*)d_in[6];
    const float* ws1    = (const float*)d_in[7];
    const float* lambd  = (const float*)d_in[8];
    float* out = (float*)d_out;

    // Workspace (floats): t0 16.8M | cx1 2.1M | t1 2.1M
    float* t0  = (float*)d_ws;
    float* cx1 = t0 + 16777216;
    float* t1  = cx1 + 2097152;

    // Level 0 fused: x -> t0 (conv+soft+scale, all 8 bands) + level-1 DWT cx1
    fused_l0_k<<<1024, 512, 0, stream>>>(x, w0, ws0, lambd, t0, cx1);
    // Level 1 conv+soft (software-pipelined)
    dwconv_soft_pipe_k<16, 4><<<512, 256, 0, stream>>>(cx1, w1, ws1, lambd, t1);
    // Final: base conv + level-1 idwt (fused) + level-0 idwt
    final_k2<<<2048, 256, 0, stream>>>(x, t0, t1, base_w, base_b, base_s, out);
}

// Round 9
// 238.866 us; speedup vs baseline: 1.1402x; 1.1402x over previous
//
#include <hip/hip_runtime.h>

#define SQ3F 0.35355339059327379f

__device__ __forceinline__ float rfl(float v) {
    return __int_as_float(__builtin_amdgcn_readfirstlane(__float_as_int(v)));
}

// Forward 2x2x2 Haar butterfly. v index = z*4+y*2+x. o index = fz*4+fy*2+fx.
__device__ __forceinline__ void haar_fwd(const float v[8], float o[8]) {
    float ax[8];
#pragma unroll
    for (int i = 0; i < 4; ++i) {
        float a = v[2 * i], b = v[2 * i + 1];
        ax[2 * i]     = a + b;
        ax[2 * i + 1] = b - a;
    }
    float ay[8];
#pragma unroll
    for (int z = 0; z < 2; ++z)
#pragma unroll
        for (int bx = 0; bx < 2; ++bx) {
            float a = ax[z * 4 + bx], b = ax[z * 4 + 2 + bx];
            ay[z * 4 + bx]     = a + b;
            ay[z * 4 + 2 + bx] = b - a;
        }
#pragma unroll
    for (int j = 0; j < 4; ++j) {
        float a = ay[j], b = ay[4 + j];
        o[j]     = (a + b) * SQ3F;
        o[4 + j] = (b - a) * SQ3F;
    }
}

// Inverse Haar. t index = fz*4+fy*2+fx. o index = z*4+y*2+x.
__device__ __forceinline__ void haar_inv(const float t[8], float o[8]) {
    float az[8];
#pragma unroll
    for (int j = 0; j < 4; ++j) {
        float lo = t[j], hi = t[4 + j];
        az[j]     = lo + hi;
        az[4 + j] = lo - hi;
    }
    float ay[8];
#pragma unroll
    for (int z = 0; z < 2; ++z)
#pragma unroll
        for (int bx = 0; bx < 2; ++bx) {
            float lo = az[z * 4 + bx], hi = az[z * 4 + 2 + bx];
            ay[z * 4 + bx]     = lo + hi;
            ay[z * 4 + 2 + bx] = lo - hi;
        }
#pragma unroll
    for (int i = 0; i < 4; ++i) {
        float lo = ay[2 * i], hi = ay[2 * i + 1];
        o[2 * i]     = (lo + hi) * SQ3F;
        o[2 * i + 1] = (lo - hi) * SQ3F;
    }
}

// ============ Fused level-0: DWT + depthwise conv + soft-threshold =========
// R7 form, FROZEN. (R8's cross-barrier prefetch buffer triggered regalloc
// collapse: VGPR clamped to 40, acc spilled, WRITE 72->192 MB. Same failure
// as R4. No more cross-barrier register state in this kernel.)
__global__ __launch_bounds__(512, 6) void fused_l0_k(
    const float* __restrict__ x, const float* __restrict__ wt,
    const float* __restrict__ wscale, const float* __restrict__ lambd_p,
    float* __restrict__ t0, float* __restrict__ cx1) {
    __shared__ __align__(16) float pl[8][32][36];
    int bx   = ((blockIdx.x & 7) << 7) + (blockIdx.x >> 3);  // XCD-chunked
    int slab = bx & 15;
    int c    = bx >> 4;
    int z0   = slab * 2;
    int tid  = threadIdx.x;

    // zero the x-pad columns once (512 pad slots, one per thread)
    {
        int fi   = tid >> 6;
        int rowi = (tid >> 1) & 31;
        pl[fi][rowi][(tid & 1) * 33] = 0.f;
    }

    int f    = __builtin_amdgcn_readfirstlane(tid >> 6);  // band, wave-uniform
    int lane = tid & 63;
    int cty  = lane >> 1;         // conv row 0..31
    int cx0i = (lane & 1) * 16;   // 16-wide x chunk
    int cc   = c * 8 + f;         // wave-uniform
    float wv[27];
    const float* wp = wt + cc * 27;
#pragma unroll
    for (int k = 0; k < 27; ++k) wv[k] = rfl(wp[k]);  // SGPRs
    float lam = rfl(*lambd_p);
    float sc  = rfl(wscale[cc]);

    const float* xc = x + ((long)c << 18);

    float acc[2][16];
#pragma unroll
    for (int s = 0; s < 2; ++s)
#pragma unroll
        for (int j = 0; j < 16; ++j) acc[s][j] = 0.f;

    float llq00 = 0.f, llq01 = 0.f;  // raw LL of plane z0 (this thread's 2 cells)

    // pp fully unrolled so acc/ring indices are compile-time constants.
#pragma unroll
    for (int pp = 0; pp < 4; ++pp) {
        int p       = z0 - 1 + pp;
        bool pvalid = (p >= 0) && (p <= 31);  // wave-uniform
        __syncthreads();
        if (pvalid) {
            // DWT plane p -> LDS (1024 cells, 2 x-adjacent cells per thread;
            // global reads are float4 = both cells' x-pairs in one load)
            int cell = 2 * tid;
            int y    = cell >> 5;
            int xx   = cell & 31;  // even
            float v0[8], v1[8];
#pragma unroll
            for (int z = 0; z < 2; ++z)
#pragma unroll
                for (int yy = 0; yy < 2; ++yy) {
                    float4 q = *(const float4*)(xc + (((2 * p + z) << 6) +
                                                      (2 * y + yy)) * 64 + 2 * xx);
                    v0[z * 4 + yy * 2]     = q.x;
                    v0[z * 4 + yy * 2 + 1] = q.y;
                    v1[z * 4 + yy * 2]     = q.z;
                    v1[z * 4 + yy * 2 + 1] = q.w;
                }
            float o0[8], o1[8];
            haar_fwd(v0, o0);
            haar_fwd(v1, o1);
#pragma unroll
            for (int k = 0; k < 8; ++k) {
                pl[k][y][xx + 1] = o0[k];
                pl[k][y][xx + 2] = o1[k];
            }
            if (pp == 1) {  // plane z0: stash raw LL for level-1 DWT
                llq00 = o0[0];
                llq01 = o1[0];
            }
            if (pp == 2) {  // plane z0+1: complete the level-1 cell, write cx1
                float l10 = o0[0], l11 = o1[0];
                // y-parity partner = lane^16 (same wave; pvalid wave-uniform)
                float p00 = __shfl_xor(llq00, 16);
                float p01 = __shfl_xor(llq01, 16);
                float p10 = __shfl_xor(l10, 16);
                float p11 = __shfl_xor(l11, 16);
                int yp = (tid >> 4) & 1;  // y parity
                float v[8];  // v[z*4 + yy*2 + xp]
                if (yp == 0) {
                    v[0] = llq00; v[1] = llq01; v[2] = p00; v[3] = p01;
                    v[4] = l10;   v[5] = l11;   v[6] = p10; v[7] = p11;
                } else {
                    v[0] = p00;   v[1] = p01;   v[2] = llq00; v[3] = llq01;
                    v[4] = p10;   v[5] = p11;   v[6] = l10;   v[7] = l11;
                }
                float o[8];
                haar_fwd(v, o);
                int d  = z0 >> 1;
                int hy = (tid >> 4) >> 1;   // y/2, 0..15
                int wx = tid & 15;          // xx/2
                int sA = (d * 16 + hy) * 16 + wx;
                int f0 = yp * 4;  // even-y writes bands 0-3, odd-y bands 4-7
#pragma unroll
                for (int q = 0; q < 4; ++q)
                    cx1[((c * 8 + f0 + q) << 12) + sA] = o[f0 + q];
            }
        }
        __syncthreads();
        if (pvalid) {
            // fold plane p into pending outputs zc = p+1-dz (rel = pp-dz)
#pragma unroll
            for (int dy = 0; dy < 3; ++dy) {
                int yy = cty - 1 + dy;
                if ((unsigned)yy < 32u) {
                    float r[18];
                    {
                        const float* rp = &pl[f][yy][cx0i];
                        float4 a0 = *(const float4*)(rp);
                        float4 a1 = *(const float4*)(rp + 4);
                        float4 a2 = *(const float4*)(rp + 8);
                        float4 a3 = *(const float4*)(rp + 12);
                        float2 a4 = *(const float2*)(rp + 16);
                        r[0]  = a0.x; r[1]  = a0.y; r[2]  = a0.z; r[3]  = a0.w;
                        r[4]  = a1.x; r[5]  = a1.y; r[6]  = a1.z; r[7]  = a1.w;
                        r[8]  = a2.x; r[9]  = a2.y; r[10] = a2.z; r[11] = a2.w;
                        r[12] = a3.x; r[13] = a3.y; r[14] = a3.z; r[15] = a3.w;
                        r[16] = a4.x; r[17] = a4.y;
                    }
#pragma unroll
                    for (int dz = 0; dz < 3; ++dz) {
                        int rel = pp - dz;
                        if (rel >= 0 && rel <= 1) {  // compile-time
#pragma unroll
                            for (int dx = 0; dx < 3; ++dx) {
                                float wgt = wv[dz * 9 + dy * 3 + dx];
#pragma unroll
                                for (int j = 0; j < 16; ++j)
                                    acc[rel][j] += r[dx + j] * wgt;
                            }
                        }
                    }
                }
            }
        }
        // finalize output zc = z0+rel (rel = pp-2) — needs planes zc-1..zc+1
        {
            int rel = pp - 2;
            if (rel >= 0 && rel <= 1) {  // compile-time
                int zc = z0 + rel;
                float res[16];
#pragma unroll
                for (int j = 0; j < 16; ++j) {
                    float t = acc[rel][j];
                    if (f != 0) {
                        float a = fabsf(t) - lam;
                        t       = a > 0.f ? copysignf(a, t) : 0.f;
                    }
                    res[j]      = t * sc;
                    acc[rel][j] = 0.f;
                }
                float* op = t0 + ((long)cc << 15) + (zc << 10) + cty * 32 + cx0i;
#pragma unroll
                for (int q = 0; q < 4; ++q)
                    *(float4*)(op + q * 4) = float4{res[q * 4], res[q * 4 + 1],
                                                    res[q * 4 + 2], res[q * 4 + 3]};
            }
        }
    }
}

// ===================== Level-1 conv kernel =====================
// R9: conv_compute rewritten with FULLY STATIC indexing — the previous
// version selected the window plane via a runtime pointer ternary
// ((dz==0)? win[SP] : ...). If LLVM fails to fold that, win[4][3][6]
// (72 floats) lands in scratch (rule #20) => ~130 MB hidden scratch
// traffic across the grid. Template-constant first index everywhere.
template <int S, int SLOT>
__device__ __forceinline__ void load_plane4(const float* __restrict__ ip,
                                            int z, int ty, int x0,
                                            float win[4][3][6]) {
    bool zok = ((unsigned)z < (unsigned)S);
    const float* pp = ip + z * S * S;
#pragma unroll
    for (int dy = 0; dy < 3; ++dy) {
        int yy  = ty - 1 + dy;
        bool yok = zok && ((unsigned)yy < (unsigned)S);
        const float* rp = pp + yy * S;
        win[SLOT][dy][0] = (yok && x0 > 0) ? rp[x0 - 1] : 0.f;
        float4 m = yok ? *(const float4*)(rp + x0) : float4{0.f, 0.f, 0.f, 0.f};
        win[SLOT][dy][1] = m.x;
        win[SLOT][dy][2] = m.y;
        win[SLOT][dy][3] = m.z;
        win[SLOT][dy][4] = m.w;
        win[SLOT][dy][5] = (yok && (x0 + 4 < S)) ? rp[x0 + 4] : 0.f;
    }
}

template <int S, int SP, int SC, int SN>
__device__ __forceinline__ void conv_compute(int zo, int ty, int x0,
                                             const float* __restrict__ wv,
                                             const float win[4][3][6], float lam,
                                             float sc, bool hf,
                                             float* __restrict__ op) {
    float acc[4] = {0.f, 0.f, 0.f, 0.f};
#pragma unroll
    for (int dy = 0; dy < 3; ++dy)
#pragma unroll
        for (int dx = 0; dx < 3; ++dx) {
            float w0 = wv[0 * 9 + dy * 3 + dx];
            float w1 = wv[1 * 9 + dy * 3 + dx];
            float w2 = wv[2 * 9 + dy * 3 + dx];
#pragma unroll
            for (int j = 0; j < 4; ++j) {
                acc[j] += win[SP][dy][dx + j] * w0;  // static first index
                acc[j] += win[SC][dy][dx + j] * w1;
                acc[j] += win[SN][dy][dx + j] * w2;
            }
        }
    float4 r;
    float* rr = (float*)&r;
#pragma unroll
    for (int j = 0; j < 4; ++j) {
        float t = acc[j];
        if (hf) {
            float a = fabsf(t) - lam;
            t       = a > 0.f ? copysignf(a, t) : 0.f;
        }
        rr[j] = t * sc;
    }
    *(float4*)(op + (zo * S + ty) * S + x0) = r;
}

// z split into 4 chunks of 4 -> grid 512 blocks; XCD-chunked swizzle.
template <int S, int CPB>
__global__ __launch_bounds__(256) void dwconv_soft_pipe_k(
    const float* __restrict__ in, const float* __restrict__ wt,
    const float* __restrict__ wscale, const float* __restrict__ lambd_p,
    float* __restrict__ out) {
    constexpr int TX = S / 4;
    int bxl = ((blockIdx.x & 7) << 6) + (blockIdx.x >> 3);  // XCD-chunked
    int tid = threadIdx.x;
    int tx  = tid % TX;
    int ty  = (tid / TX) % S;
    int cs  = tid / (TX * S);
    int zc  = bxl & 3;
    int cg  = bxl >> 2;
    int cc  = cg * CPB + cs;
    const float* ip = in + (long)cc * (S * S * S);
    float* op       = out + (long)cc * (S * S * S);
    float wv[27];
#pragma unroll
    for (int k = 0; k < 27; ++k) wv[k] = wt[cc * 27 + k];
    float lam = *lambd_p;
    float sc  = wscale[cc];
    bool hf   = (cc & 7) != 0;
    int x0    = 4 * tx;
    int z0    = 4 * zc;  // multiple of 4 -> slot = plane & 3

    float win[4][3][6];
    load_plane4<S, 3>(ip, z0 - 1, ty, x0, win);  // (-1)&3 == 3
    load_plane4<S, 0>(ip, z0,     ty, x0, win);
    load_plane4<S, 1>(ip, z0 + 1, ty, x0, win);
    load_plane4<S, 2>(ip, z0 + 2, ty, x0, win);
    conv_compute<S, 3, 0, 1>(z0, ty, x0, wv, win, lam, sc, hf, op);
    load_plane4<S, 3>(ip, z0 + 3, ty, x0, win);
    conv_compute<S, 0, 1, 2>(z0 + 1, ty, x0, wv, win, lam, sc, hf, op);
    load_plane4<S, 0>(ip, z0 + 4, ty, x0, win);
    conv_compute<S, 1, 2, 3>(z0 + 2, ty, x0, wv, win, lam, sc, hf, op);
    conv_compute<S, 2, 3, 0>(z0 + 3, ty, x0, wv, win, lam, sc, hf, op);
}

// ========== Final: LDS-tiled base conv + level-1 idwt + level-0 idwt =======
// FROZEN (R7 form): tile/mapping/epilogue-hoist validated. 79 µs, traffic
// near-ideal (FETCH 79 MB / WRITE 70 MB).
__global__ __launch_bounds__(256, 3) void final_k2(
    const float* __restrict__ x, const float* __restrict__ t0,
    const float* __restrict__ t1, const float* __restrict__ bw,
    const float* __restrict__ bb, const float* __restrict__ bscale,
    float* __restrict__ out) {
    __shared__ float xs[18 * 10 * 67];
    int bx = blockIdx.x;
    int c  = bx >> 5;
    int ti = bx & 31;
    int dt = ti >> 3;  // z tile (16 thick)
    int ht = ti & 7;   // y tile (8 thick)
    const float* xc = x + ((long)c << 18);

    int tid = threadIdx.x;
    int wc  = tid & 7;         // x chunk: cells w0..w0+3
    int hc  = (tid >> 3) & 3;  // h cell in tile
    int dc  = tid >> 5;        // d cell in tile
    int d   = dt * 8 + dc;
    int h   = ht * 4 + hc;
    int w0  = wc * 4;

    // ---- epilogue data: issue loads FIRST (independent of xs) ----
    int cell0 = (d << 10) + (h << 5) + w0;
    float4 t0v[8];
#pragma unroll
    for (int f = 0; f < 8; ++f)
        t0v[f] = *(const float4*)(t0 + (((long)(c * 8 + f)) << 15) + cell0);
    int s1b = ((d >> 1) * 16 + (h >> 1)) * 16 + (w0 >> 1);
    float2 t1v[8];
#pragma unroll
    for (int f = 0; f < 8; ++f)
        t1v[f] = *(const float2*)(t1 + ((c * 8 + f) << 12) + s1b);

    // ---- stage x tile ----
    int zg0 = 16 * dt - 1, yg0 = 8 * ht - 1;
    for (int i = tid; i < 18 * 10 * 66; i += 256) {
        int pz = i / 660;
        int r  = i - pz * 660;
        int py = r / 66;
        int px = r - py * 66;
        int zg = zg0 + pz, yg = yg0 + py, xg = px - 1;
        bool ok = ((unsigned)zg < 64u) && ((unsigned)yg < 64u) && ((unsigned)xg < 64u);
        xs[(pz * 10 + py) * 67 + px] = ok ? xc[(zg << 12) + (yg << 6) + xg] : 0.f;
    }
    const float* wp0 = bw + c * 27;
    float wv[27];
#pragma unroll
    for (int k = 0; k < 27; ++k) wv[k] = wp0[k];
    float bias = bb[c], scl = bscale[c];
    __syncthreads();

    float acc[2][2][8];
#pragma unroll
    for (int oz = 0; oz < 2; ++oz)
#pragma unroll
        for (int oy = 0; oy < 2; ++oy)
#pragma unroll
            for (int m = 0; m < 8; ++m) acc[oz][oy][m] = 0.f;

#pragma unroll
    for (int pz = 0; pz < 4; ++pz) {
        float r[4][10];
#pragma unroll
        for (int py = 0; py < 4; ++py)
#pragma unroll
            for (int k = 0; k < 10; ++k)
                r[py][k] = xs[((2 * dc + pz) * 10 + (2 * hc + py)) * 67 + 8 * wc + k];
#pragma unroll
        for (int oz = 0; oz < 2; ++oz) {
            int kz = pz - oz;
            if (kz >= 0 && kz <= 2) {
#pragma unroll
                for (int py = 0; py < 4; ++py)
#pragma unroll
                    for (int oy = 0; oy < 2; ++oy) {
                        int ky = py - oy;
                        if (ky >= 0 && ky <= 2) {
#pragma unroll
                            for (int kx = 0; kx < 3; ++kx) {
                                float wgt = wv[kz * 9 + ky * 3 + kx];
#pragma unroll
                                for (int m = 0; m < 8; ++m)
                                    acc[oz][oy][m] += r[py][m + kx] * wgt;
                            }
                        }
                    }
            }
        }
    }

    // epilogue: t0/t1 already in registers; idwt + store
#pragma unroll
    for (int j = 0; j < 4; ++j) {
        int w = w0 + j;
        float tf[8];
#pragma unroll
        for (int f = 0; f < 8; ++f) tf[f] = ((const float*)&t0v[f])[j];
        float add = 0.f;
#pragma unroll
        for (int f = 0; f < 8; ++f) {
            float v  = (j >> 1) ? t1v[f].y : t1v[f].x;
            float sg = 1.f;
            if ((f & 4) && (d & 1)) sg = -sg;
            if ((f & 2) && (h & 1)) sg = -sg;
            if ((f & 1) && (j & 1)) sg = -sg;
            add += sg * v;
        }
        tf[0] += add * SQ3F;
        float contrib[8];
        haar_inv(tf, contrib);
#pragma unroll
        for (int oz = 0; oz < 2; ++oz)
#pragma unroll
            for (int oy = 0; oy < 2; ++oy) {
                float2 rr;
                rr.x = (acc[oz][oy][2 * j] + bias) * scl + contrib[oz * 4 + oy * 2];
                rr.y = (acc[oz][oy][2 * j + 1] + bias) * scl +
                       contrib[oz * 4 + oy * 2 + 1];
                *(float2*)(out + ((long)c << 18) + ((2 * d + oz) << 12) +
                           ((2 * h + oy) << 6) + 2 * w) = rr;
            }
    }
}

extern "C" void kernel_launch(void* const* d_in, const int* in_sizes, int n_in,
                              void* d_out, int out_size, void* d_ws, size_t ws_size,
                              hipStream_t stream) {
    const float* x      = (const float*)d_in[0];
    const float* base_w = (const float*)d_in[1];
    const float* base_b = (const float*)d_in[2];
    const float* base_s = (const float*)d_in[3];
    const float* w0     = (const float*)d_in[4];
    const float* w1     = (const float*)d_in[5];
    const float* ws0    = (const float*)d_in[6];
    const float* ws1    = (const float*)d_in[7];
    const float* lambd  = (const float*)d_in[8];
    float* out = (float*)d_out;

    // Workspace (floats): t0 16.8M | cx1 2.1M | t1 2.1M
    float* t0  = (float*)d_ws;
    float* cx1 = t0 + 16777216;
    float* t1  = cx1 + 2097152;

    // Level 0 fused: x -> t0 (conv+soft+scale, all 8 bands) + level-1 DWT cx1
    fused_l0_k<<<1024, 512, 0, stream>>>(x, w0, ws0, lambd, t0, cx1);
    // Level 1 conv+soft (software-pipelined, static-indexed window)
    dwconv_soft_pipe_k<16, 4><<<512, 256, 0, stream>>>(cx1, w1, ws1, lambd, t1);
    // Final: base conv + level-1 idwt (fused) + level-0 idwt
    final_k2<<<2048, 256, 0, stream>>>(x, t0, t1, base_w, base_b, base_s, out);
}

// Round 10
// 217.821 us; speedup vs baseline: 1.2504x; 1.0966x over previous
//
#include <hip/hip_runtime.h>

#define SQ3F 0.35355339059327379f

__device__ __forceinline__ float rfl(float v) {
    return __int_as_float(__builtin_amdgcn_readfirstlane(__float_as_int(v)));
}

// Forward 2x2x2 Haar butterfly. v index = z*4+y*2+x. o index = fz*4+fy*2+fx.
__device__ __forceinline__ void haar_fwd(const float v[8], float o[8]) {
    float ax[8];
#pragma unroll
    for (int i = 0; i < 4; ++i) {
        float a = v[2 * i], b = v[2 * i + 1];
        ax[2 * i]     = a + b;
        ax[2 * i + 1] = b - a;
    }
    float ay[8];
#pragma unroll
    for (int z = 0; z < 2; ++z)
#pragma unroll
        for (int bx = 0; bx < 2; ++bx) {
            float a = ax[z * 4 + bx], b = ax[z * 4 + 2 + bx];
            ay[z * 4 + bx]     = a + b;
            ay[z * 4 + 2 + bx] = b - a;
        }
#pragma unroll
    for (int j = 0; j < 4; ++j) {
        float a = ay[j], b = ay[4 + j];
        o[j]     = (a + b) * SQ3F;
        o[4 + j] = (b - a) * SQ3F;
    }
}

// Inverse Haar. t index = fz*4+fy*2+fx. o index = z*4+y*2+x.
__device__ __forceinline__ void haar_inv(const float t[8], float o[8]) {
    float az[8];
#pragma unroll
    for (int j = 0; j < 4; ++j) {
        float lo = t[j], hi = t[4 + j];
        az[j]     = lo + hi;
        az[4 + j] = lo - hi;
    }
    float ay[8];
#pragma unroll
    for (int z = 0; z < 2; ++z)
#pragma unroll
        for (int bx = 0; bx < 2; ++bx) {
            float lo = az[z * 4 + bx], hi = az[z * 4 + 2 + bx];
            ay[z * 4 + bx]     = lo + hi;
            ay[z * 4 + 2 + bx] = lo - hi;
        }
#pragma unroll
    for (int i = 0; i < 4; ++i) {
        float lo = ay[2 * i], hi = ay[2 * i + 1];
        o[2 * i]     = (lo + hi) * SQ3F;
        o[2 * i + 1] = (lo - hi) * SQ3F;
    }
}

// ============ Fused level-0: DWT + depthwise conv + soft-threshold =========
// FROZEN (R7/R9 form). Traffic near-ideal: FETCH 68.5 / WRITE 82 MB.
// Cross-barrier register prefetch forbidden (R8: regalloc collapse->spill).
__global__ __launch_bounds__(512, 6) void fused_l0_k(
    const float* __restrict__ x, const float* __restrict__ wt,
    const float* __restrict__ wscale, const float* __restrict__ lambd_p,
    float* __restrict__ t0, float* __restrict__ cx1) {
    __shared__ __align__(16) float pl[8][32][36];
    int bx   = ((blockIdx.x & 7) << 7) + (blockIdx.x >> 3);  // XCD-chunked
    int slab = bx & 15;
    int c    = bx >> 4;
    int z0   = slab * 2;
    int tid  = threadIdx.x;

    // zero the x-pad columns once (512 pad slots, one per thread)
    {
        int fi   = tid >> 6;
        int rowi = (tid >> 1) & 31;
        pl[fi][rowi][(tid & 1) * 33] = 0.f;
    }

    int f    = __builtin_amdgcn_readfirstlane(tid >> 6);  // band, wave-uniform
    int lane = tid & 63;
    int cty  = lane >> 1;         // conv row 0..31
    int cx0i = (lane & 1) * 16;   // 16-wide x chunk
    int cc   = c * 8 + f;         // wave-uniform
    float wv[27];
    const float* wp = wt + cc * 27;
#pragma unroll
    for (int k = 0; k < 27; ++k) wv[k] = rfl(wp[k]);  // SGPRs
    float lam = rfl(*lambd_p);
    float sc  = rfl(wscale[cc]);

    const float* xc = x + ((long)c << 18);

    float acc[2][16];
#pragma unroll
    for (int s = 0; s < 2; ++s)
#pragma unroll
        for (int j = 0; j < 16; ++j) acc[s][j] = 0.f;

    float llq00 = 0.f, llq01 = 0.f;  // raw LL of plane z0 (this thread's 2 cells)

    // pp fully unrolled so acc/ring indices are compile-time constants.
#pragma unroll
    for (int pp = 0; pp < 4; ++pp) {
        int p       = z0 - 1 + pp;
        bool pvalid = (p >= 0) && (p <= 31);  // wave-uniform
        __syncthreads();
        if (pvalid) {
            // DWT plane p -> LDS (1024 cells, 2 x-adjacent cells per thread;
            // global reads are float4 = both cells' x-pairs in one load)
            int cell = 2 * tid;
            int y    = cell >> 5;
            int xx   = cell & 31;  // even
            float v0[8], v1[8];
#pragma unroll
            for (int z = 0; z < 2; ++z)
#pragma unroll
                for (int yy = 0; yy < 2; ++yy) {
                    float4 q = *(const float4*)(xc + (((2 * p + z) << 6) +
                                                      (2 * y + yy)) * 64 + 2 * xx);
                    v0[z * 4 + yy * 2]     = q.x;
                    v0[z * 4 + yy * 2 + 1] = q.y;
                    v1[z * 4 + yy * 2]     = q.z;
                    v1[z * 4 + yy * 2 + 1] = q.w;
                }
            float o0[8], o1[8];
            haar_fwd(v0, o0);
            haar_fwd(v1, o1);
#pragma unroll
            for (int k = 0; k < 8; ++k) {
                pl[k][y][xx + 1] = o0[k];
                pl[k][y][xx + 2] = o1[k];
            }
            if (pp == 1) {  // plane z0: stash raw LL for level-1 DWT
                llq00 = o0[0];
                llq01 = o1[0];
            }
            if (pp == 2) {  // plane z0+1: complete the level-1 cell, write cx1
                float l10 = o0[0], l11 = o1[0];
                // y-parity partner = lane^16 (same wave; pvalid wave-uniform)
                float p00 = __shfl_xor(llq00, 16);
                float p01 = __shfl_xor(llq01, 16);
                float p10 = __shfl_xor(l10, 16);
                float p11 = __shfl_xor(l11, 16);
                int yp = (tid >> 4) & 1;  // y parity
                float v[8];  // v[z*4 + yy*2 + xp]
                if (yp == 0) {
                    v[0] = llq00; v[1] = llq01; v[2] = p00; v[3] = p01;
                    v[4] = l10;   v[5] = l11;   v[6] = p10; v[7] = p11;
                } else {
                    v[0] = p00;   v[1] = p01;   v[2] = llq00; v[3] = llq01;
                    v[4] = p10;   v[5] = p11;   v[6] = l10;   v[7] = l11;
                }
                float o[8];
                haar_fwd(v, o);
                int d  = z0 >> 1;
                int hy = (tid >> 4) >> 1;   // y/2, 0..15
                int wx = tid & 15;          // xx/2
                int sA = (d * 16 + hy) * 16 + wx;
                int f0 = yp * 4;  // even-y writes bands 0-3, odd-y bands 4-7
#pragma unroll
                for (int q = 0; q < 4; ++q)
                    cx1[((c * 8 + f0 + q) << 12) + sA] = o[f0 + q];
            }
        }
        __syncthreads();
        if (pvalid) {
            // fold plane p into pending outputs zc = p+1-dz (rel = pp-dz)
#pragma unroll
            for (int dy = 0; dy < 3; ++dy) {
                int yy = cty - 1 + dy;
                if ((unsigned)yy < 32u) {
                    float r[18];
                    {
                        const float* rp = &pl[f][yy][cx0i];
                        float4 a0 = *(const float4*)(rp);
                        float4 a1 = *(const float4*)(rp + 4);
                        float4 a2 = *(const float4*)(rp + 8);
                        float4 a3 = *(const float4*)(rp + 12);
                        float2 a4 = *(const float2*)(rp + 16);
                        r[0]  = a0.x; r[1]  = a0.y; r[2]  = a0.z; r[3]  = a0.w;
                        r[4]  = a1.x; r[5]  = a1.y; r[6]  = a1.z; r[7]  = a1.w;
                        r[8]  = a2.x; r[9]  = a2.y; r[10] = a2.z; r[11] = a2.w;
                        r[12] = a3.x; r[13] = a3.y; r[14] = a3.z; r[15] = a3.w;
                        r[16] = a4.x; r[17] = a4.y;
                    }
#pragma unroll
                    for (int dz = 0; dz < 3; ++dz) {
                        int rel = pp - dz;
                        if (rel >= 0 && rel <= 1) {  // compile-time
#pragma unroll
                            for (int dx = 0; dx < 3; ++dx) {
                                float wgt = wv[dz * 9 + dy * 3 + dx];
#pragma unroll
                                for (int j = 0; j < 16; ++j)
                                    acc[rel][j] += r[dx + j] * wgt;
                            }
                        }
                    }
                }
            }
        }
        // finalize output zc = z0+rel (rel = pp-2) — needs planes zc-1..zc+1
        {
            int rel = pp - 2;
            if (rel >= 0 && rel <= 1) {  // compile-time
                int zc = z0 + rel;
                float res[16];
#pragma unroll
                for (int j = 0; j < 16; ++j) {
                    float t = acc[rel][j];
                    if (f != 0) {
                        float a = fabsf(t) - lam;
                        t       = a > 0.f ? copysignf(a, t) : 0.f;
                    }
                    res[j]      = t * sc;
                    acc[rel][j] = 0.f;
                }
                float* op = t0 + ((long)cc << 15) + (zc << 10) + cty * 32 + cx0i;
#pragma unroll
                for (int q = 0; q < 4; ++q)
                    *(float4*)(op + q * 4) = float4{res[q * 4], res[q * 4 + 1],
                                                    res[q * 4 + 2], res[q * 4 + 3]};
            }
        }
    }
}

// ===================== Level-1 conv kernel =====================
template <int S, int SLOT>
__device__ __forceinline__ void load_plane4(const float* __restrict__ ip,
                                            int z, int ty, int x0,
                                            float win[4][3][6]) {
    bool zok = ((unsigned)z < (unsigned)S);
    const float* pp = ip + z * S * S;
#pragma unroll
    for (int dy = 0; dy < 3; ++dy) {
        int yy  = ty - 1 + dy;
        bool yok = zok && ((unsigned)yy < (unsigned)S);
        const float* rp = pp + yy * S;
        win[SLOT][dy][0] = (yok && x0 > 0) ? rp[x0 - 1] : 0.f;
        float4 m = yok ? *(const float4*)(rp + x0) : float4{0.f, 0.f, 0.f, 0.f};
        win[SLOT][dy][1] = m.x;
        win[SLOT][dy][2] = m.y;
        win[SLOT][dy][3] = m.z;
        win[SLOT][dy][4] = m.w;
        win[SLOT][dy][5] = (yok && (x0 + 4 < S)) ? rp[x0 + 4] : 0.f;
    }
}

template <int S, int SP, int SC, int SN>
__device__ __forceinline__ void conv_compute(int zo, int ty, int x0,
                                             const float* __restrict__ wv,
                                             const float win[4][3][6], float lam,
                                             float sc, bool hf,
                                             float* __restrict__ op) {
    float acc[4] = {0.f, 0.f, 0.f, 0.f};
#pragma unroll
    for (int dy = 0; dy < 3; ++dy)
#pragma unroll
        for (int dx = 0; dx < 3; ++dx) {
            float w0 = wv[0 * 9 + dy * 3 + dx];
            float w1 = wv[1 * 9 + dy * 3 + dx];
            float w2 = wv[2 * 9 + dy * 3 + dx];
#pragma unroll
            for (int j = 0; j < 4; ++j) {
                acc[j] += win[SP][dy][dx + j] * w0;  // static first index
                acc[j] += win[SC][dy][dx + j] * w1;
                acc[j] += win[SN][dy][dx + j] * w2;
            }
        }
    float4 r;
    float* rr = (float*)&r;
#pragma unroll
    for (int j = 0; j < 4; ++j) {
        float t = acc[j];
        if (hf) {
            float a = fabsf(t) - lam;
            t       = a > 0.f ? copysignf(a, t) : 0.f;
        }
        rr[j] = t * sc;
    }
    *(float4*)(op + (zo * S + ty) * S + x0) = r;
}

// R10: 2-plane chunks -> grid 1024 (4 blocks/CU, was 2), serial chain
// 6->4 plane-loads, ALL 4 issued before any compute (full MLP). cx1 is
// L2-resident so the 2x plane re-read is ~free. XCD-chunked swizzle.
template <int S, int CPB>
__global__ __launch_bounds__(256) void dwconv_soft_pipe_k(
    const float* __restrict__ in, const float* __restrict__ wt,
    const float* __restrict__ wscale, const float* __restrict__ lambd_p,
    float* __restrict__ out) {
    constexpr int TX = S / 4;
    int bxl = ((blockIdx.x & 7) << 7) + (blockIdx.x >> 3);  // XCD-chunked, 1024
    int tid = threadIdx.x;
    int tx  = tid % TX;
    int ty  = (tid / TX) % S;
    int cs  = tid / (TX * S);
    int zc  = bxl & 7;   // 8 z-chunks of 2
    int cg  = bxl >> 3;  // 128 channel groups
    int cc  = cg * CPB + cs;
    const float* ip = in + (long)cc * (S * S * S);
    float* op       = out + (long)cc * (S * S * S);
    float wv[27];
#pragma unroll
    for (int k = 0; k < 27; ++k) wv[k] = wt[cc * 27 + k];
    float lam = *lambd_p;
    float sc  = wscale[cc];
    bool hf   = (cc & 7) != 0;
    int x0    = 4 * tx;
    int z0    = 2 * zc;  // slot of plane q = q & 3

    float win[4][3][6];
    if ((zc & 1) == 0) {  // z0 % 4 == 0
        load_plane4<S, 3>(ip, z0 - 1, ty, x0, win);
        load_plane4<S, 0>(ip, z0,     ty, x0, win);
        load_plane4<S, 1>(ip, z0 + 1, ty, x0, win);
        load_plane4<S, 2>(ip, z0 + 2, ty, x0, win);
        conv_compute<S, 3, 0, 1>(z0,     ty, x0, wv, win, lam, sc, hf, op);
        conv_compute<S, 0, 1, 2>(z0 + 1, ty, x0, wv, win, lam, sc, hf, op);
    } else {              // z0 % 4 == 2
        load_plane4<S, 1>(ip, z0 - 1, ty, x0, win);
        load_plane4<S, 2>(ip, z0,     ty, x0, win);
        load_plane4<S, 3>(ip, z0 + 1, ty, x0, win);
        load_plane4<S, 0>(ip, z0 + 2, ty, x0, win);
        conv_compute<S, 1, 2, 3>(z0,     ty, x0, wv, win, lam, sc, hf, op);
        conv_compute<S, 2, 3, 0>(z0 + 1, ty, x0, wv, win, lam, sc, hf, op);
    }
}

// ========== Final: LDS-tiled base conv + level-1 idwt + level-0 idwt =======
// Tile/mapping/epilogue-hoist FROZEN. R10: staging loop batched — 5 loads
// issued into registers before their 5 LDS writes (was 1 load in flight per
// wave through 46 serial iterations => MLP ~2, capping the kernel at
// 1.95 TB/s). Addresses and traffic byte-identical; +10 VGPR (<=170 cap).
__global__ __launch_bounds__(256, 3) void final_k2(
    const float* __restrict__ x, const float* __restrict__ t0,
    const float* __restrict__ t1, const float* __restrict__ bw,
    const float* __restrict__ bb, const float* __restrict__ bscale,
    float* __restrict__ out) {
    __shared__ float xs[18 * 10 * 67];
    int bx = blockIdx.x;
    int c  = bx >> 5;
    int ti = bx & 31;
    int dt = ti >> 3;  // z tile (16 thick)
    int ht = ti & 7;   // y tile (8 thick)
    const float* xc = x + ((long)c << 18);

    int tid = threadIdx.x;
    int wc  = tid & 7;         // x chunk: cells w0..w0+3
    int hc  = (tid >> 3) & 3;  // h cell in tile
    int dc  = tid >> 5;        // d cell in tile
    int d   = dt * 8 + dc;
    int h   = ht * 4 + hc;
    int w0  = wc * 4;

    // ---- epilogue data: issue loads FIRST (independent of xs) ----
    int cell0 = (d << 10) + (h << 5) + w0;
    float4 t0v[8];
#pragma unroll
    for (int f = 0; f < 8; ++f)
        t0v[f] = *(const float4*)(t0 + (((long)(c * 8 + f)) << 15) + cell0);
    int s1b = ((d >> 1) * 16 + (h >> 1)) * 16 + (w0 >> 1);
    float2 t1v[8];
#pragma unroll
    for (int f = 0; f < 8; ++f)
        t1v[f] = *(const float2*)(t1 + ((c * 8 + f) << 12) + s1b);

    // ---- stage x tile: batched (5 loads in flight per batch) ----
    int zg0 = 16 * dt - 1, yg0 = 8 * ht - 1;
    constexpr int TOT = 18 * 10 * 66;  // 11880
#pragma unroll 1
    for (int k = 0; k < 10; ++k) {
        float v[5];
        int off[5];
#pragma unroll
        for (int b = 0; b < 5; ++b) {
            int i  = tid + (k * 5 + b) * 256;
            v[b]   = 0.f;
            off[b] = -1;
            if (i < TOT) {
                int pz = i / 660;
                int r  = i - pz * 660;
                int py = r / 66;
                int px = r - py * 66;
                int zg = zg0 + pz, yg = yg0 + py, xg = px - 1;
                bool ok = ((unsigned)zg < 64u) && ((unsigned)yg < 64u) &&
                          ((unsigned)xg < 64u);
                if (ok) v[b] = xc[(zg << 12) + (yg << 6) + xg];
                off[b] = (pz * 10 + py) * 67 + px;
            }
        }
#pragma unroll
        for (int b = 0; b < 5; ++b)
            if (off[b] >= 0) xs[off[b]] = v[b];
    }
    const float* wp0 = bw + c * 27;
    float wv[27];
#pragma unroll
    for (int k = 0; k < 27; ++k) wv[k] = wp0[k];
    float bias = bb[c], scl = bscale[c];
    __syncthreads();

    float acc[2][2][8];
#pragma unroll
    for (int oz = 0; oz < 2; ++oz)
#pragma unroll
        for (int oy = 0; oy < 2; ++oy)
#pragma unroll
            for (int m = 0; m < 8; ++m) acc[oz][oy][m] = 0.f;

#pragma unroll
    for (int pz = 0; pz < 4; ++pz) {
        float r[4][10];
#pragma unroll
        for (int py = 0; py < 4; ++py)
#pragma unroll
            for (int k = 0; k < 10; ++k)
                r[py][k] = xs[((2 * dc + pz) * 10 + (2 * hc + py)) * 67 + 8 * wc + k];
#pragma unroll
        for (int oz = 0; oz < 2; ++oz) {
            int kz = pz - oz;
            if (kz >= 0 && kz <= 2) {
#pragma unroll
                for (int py = 0; py < 4; ++py)
#pragma unroll
                    for (int oy = 0; oy < 2; ++oy) {
                        int ky = py - oy;
                        if (ky >= 0 && ky <= 2) {
#pragma unroll
                            for (int kx = 0; kx < 3; ++kx) {
                                float wgt = wv[kz * 9 + ky * 3 + kx];
#pragma unroll
                                for (int m = 0; m < 8; ++m)
                                    acc[oz][oy][m] += r[py][m + kx] * wgt;
                            }
                        }
                    }
            }
        }
    }

    // epilogue: t0/t1 already in registers; idwt + store
#pragma unroll
    for (int j = 0; j < 4; ++j) {
        int w = w0 + j;
        float tf[8];
#pragma unroll
        for (int f = 0; f < 8; ++f) tf[f] = ((const float*)&t0v[f])[j];
        float add = 0.f;
#pragma unroll
        for (int f = 0; f < 8; ++f) {
            float v  = (j >> 1) ? t1v[f].y : t1v[f].x;
            float sg = 1.f;
            if ((f & 4) && (d & 1)) sg = -sg;
            if ((f & 2) && (h & 1)) sg = -sg;
            if ((f & 1) && (j & 1)) sg = -sg;
            add += sg * v;
        }
        tf[0] += add * SQ3F;
        float contrib[8];
        haar_inv(tf, contrib);
#pragma unroll
        for (int oz = 0; oz < 2; ++oz)
#pragma unroll
            for (int oy = 0; oy < 2; ++oy) {
                float2 rr;
                rr.x = (acc[oz][oy][2 * j] + bias) * scl + contrib[oz * 4 + oy * 2];
                rr.y = (acc[oz][oy][2 * j + 1] + bias) * scl +
                       contrib[oz * 4 + oy * 2 + 1];
                *(float2*)(out + ((long)c << 18) + ((2 * d + oz) << 12) +
                           ((2 * h + oy) << 6) + 2 * w) = rr;
            }
    }
}

extern "C" void kernel_launch(void* const* d_in, const int* in_sizes, int n_in,
                              void* d_out, int out_size, void* d_ws, size_t ws_size,
                              hipStream_t stream) {
    const float* x      = (const float*)d_in[0];
    const float* base_w = (const float*)d_in[1];
    const float* base_b = (const float*)d_in[2];
    const float* base_s = (const float*)d_in[3];
    const float* w0     = (const float*)d_in[4];
    const float* w1     = (const float*)d_in[5];
    const float* ws0    = (const float*)d_in[6];
    const float* ws1    = (const float*)d_in[7];
    const float* lambd  = (const float*)d_in[8];
    float* out = (float*)d_out;

    // Workspace (floats): t0 16.8M | cx1 2.1M | t1 2.1M
    float* t0  = (float*)d_ws;
    float* cx1 = t0 + 16777216;
    float* t1  = cx1 + 2097152;

    // Level 0 fused: x -> t0 (conv+soft+scale, all 8 bands) + level-1 DWT cx1
    fused_l0_k<<<1024, 512, 0, stream>>>(x, w0, ws0, lambd, t0, cx1);
    // Level 1 conv+soft (2-plane chunks, 1024 blocks)
    dwconv_soft_pipe_k<16, 4><<<1024, 256, 0, stream>>>(cx1, w1, ws1, lambd, t1);
    // Final: base conv + level-1 idwt (fused) + level-0 idwt
    final_k2<<<2048, 256, 0, stream>>>(x, t0, t1, base_w, base_b, base_s, out);
}

// Round 11
// 208.513 us; speedup vs baseline: 1.3062x; 1.0446x over previous
//
#include <hip/hip_runtime.h>

#define SQ3F 0.35355339059327379f

__device__ __forceinline__ float rfl(float v) {
    return __int_as_float(__builtin_amdgcn_readfirstlane(__float_as_int(v)));
}

// Forward 2x2x2 Haar butterfly. v index = z*4+y*2+x. o index = fz*4+fy*2+fx.
__device__ __forceinline__ void haar_fwd(const float v[8], float o[8]) {
    float ax[8];
#pragma unroll
    for (int i = 0; i < 4; ++i) {
        float a = v[2 * i], b = v[2 * i + 1];
        ax[2 * i]     = a + b;
        ax[2 * i + 1] = b - a;
    }
    float ay[8];
#pragma unroll
    for (int z = 0; z < 2; ++z)
#pragma unroll
        for (int bx = 0; bx < 2; ++bx) {
            float a = ax[z * 4 + bx], b = ax[z * 4 + 2 + bx];
            ay[z * 4 + bx]     = a + b;
            ay[z * 4 + 2 + bx] = b - a;
        }
#pragma unroll
    for (int j = 0; j < 4; ++j) {
        float a = ay[j], b = ay[4 + j];
        o[j]     = (a + b) * SQ3F;
        o[4 + j] = (b - a) * SQ3F;
    }
}

// Inverse Haar. t index = fz*4+fy*2+fx. o index = z*4+y*2+x.
__device__ __forceinline__ void haar_inv(const float t[8], float o[8]) {
    float az[8];
#pragma unroll
    for (int j = 0; j < 4; ++j) {
        float lo = t[j], hi = t[4 + j];
        az[j]     = lo + hi;
        az[4 + j] = lo - hi;
    }
    float ay[8];
#pragma unroll
    for (int z = 0; z < 2; ++z)
#pragma unroll
        for (int bx = 0; bx < 2; ++bx) {
            float lo = az[z * 4 + bx], hi = az[z * 4 + 2 + bx];
            ay[z * 4 + bx]     = lo + hi;
            ay[z * 4 + 2 + bx] = lo - hi;
        }
#pragma unroll
    for (int i = 0; i < 4; ++i) {
        float lo = ay[2 * i], hi = ay[2 * i + 1];
        o[2 * i]     = (lo + hi) * SQ3F;
        o[2 * i + 1] = (lo - hi) * SQ3F;
    }
}

// ============ Fused level-0: DWT + depthwise conv + soft-threshold =========
// R11: LDS double-buffer pipeline. R10's form had load-issue duty cycle
// ~50% (no global loads in flight during fold half of each phase) => 2.5
// of 6.3 TB/s. Now: 5 phases, 1 barrier each; per phase issue loads(plane i)
// -> sched_barrier(0) (pin issue above fold; R3's sinking fix) -> fold
// plane i-1 from OTHER buffer -> finalize -> consume loads + write this
// buffer -> barrier. Prefetch regs consumed BEFORE the barrier (no
// cross-barrier state: R4/R8 spill trigger structurally absent).
// LDS 72KB -> 2 blocks/CU; launch_bounds (512,4) => VGPR cap 128.
__global__ __launch_bounds__(512, 4) void fused_l0_k(
    const float* __restrict__ x, const float* __restrict__ wt,
    const float* __restrict__ wscale, const float* __restrict__ lambd_p,
    float* __restrict__ t0, float* __restrict__ cx1) {
    __shared__ __align__(16) float pl[2][8][32][36];
    int bx   = ((blockIdx.x & 7) << 7) + (blockIdx.x >> 3);  // XCD-chunked
    int slab = bx & 15;
    int c    = bx >> 4;
    int z0   = slab * 2;
    int tid  = threadIdx.x;

    // zero the x-pad columns of BOTH buffers once
    {
        int fi   = tid >> 6;
        int rowi = (tid >> 1) & 31;
        pl[0][fi][rowi][(tid & 1) * 33] = 0.f;
        pl[1][fi][rowi][(tid & 1) * 33] = 0.f;
    }

    int f    = __builtin_amdgcn_readfirstlane(tid >> 6);  // band, wave-uniform
    int lane = tid & 63;
    int cty  = lane >> 1;         // conv row 0..31
    int cx0i = (lane & 1) * 16;   // 16-wide x chunk
    int cc   = c * 8 + f;         // wave-uniform
    float wv[27];
    const float* wp = wt + cc * 27;
#pragma unroll
    for (int k = 0; k < 27; ++k) wv[k] = rfl(wp[k]);  // SGPRs
    float lam = rfl(*lambd_p);
    float sc  = rfl(wscale[cc]);

    const float* xc = x + ((long)c << 18);

    // staging cell geometry (2 x-adjacent cells per thread)
    int cell = 2 * tid;
    int y    = cell >> 5;
    int xx   = cell & 31;  // even

    float4 pre[4];  // prefetch: pre[z*2+yy]; consumed within the same phase
    auto issue_loads = [&](int p) {
#pragma unroll
        for (int z = 0; z < 2; ++z)
#pragma unroll
            for (int yy = 0; yy < 2; ++yy)
                pre[z * 2 + yy] = *(const float4*)(
                    xc + (((2 * p + z) << 6) + (2 * y + yy)) * 64 + 2 * xx);
    };

    float acc[2][16];
#pragma unroll
    for (int s = 0; s < 2; ++s)
#pragma unroll
        for (int j = 0; j < 16; ++j) acc[s][j] = 0.f;

    float llq00 = 0.f, llq01 = 0.f;  // raw LL of plane z0 (2 scalars, as before)

    // 5 phases: phase i stages plane p=z0-1+i (i<4) into buf i&1 and folds
    // plane p-1 from buf (i-1)&1. One barrier per phase.
#pragma unroll
    for (int i = 0; i < 5; ++i) {
        int p    = z0 - 1 + i;                         // staged this phase
        bool sv  = (i < 4) && (p >= 0) && (p <= 31);   // wave-uniform
        int pf   = z0 - 2 + i;                         // folded this phase
        bool fv  = (i >= 1) && (pf >= 0) && (pf <= 31);

        if (sv) {
            issue_loads(p);
            __builtin_amdgcn_sched_barrier(0);  // loads must not sink below
        }

        if (fv) {
            // fold plane pf (plane-index pp = i-1) from buf (i-1)&1
            constexpr int dummy = 0; (void)dummy;
#pragma unroll
            for (int dy = 0; dy < 3; ++dy) {
                int yy = cty - 1 + dy;
                if ((unsigned)yy < 32u) {
                    float r[18];
                    {
                        const float* rp = &pl[(i - 1) & 1][f][yy][cx0i];
                        float4 a0 = *(const float4*)(rp);
                        float4 a1 = *(const float4*)(rp + 4);
                        float4 a2 = *(const float4*)(rp + 8);
                        float4 a3 = *(const float4*)(rp + 12);
                        float2 a4 = *(const float2*)(rp + 16);
                        r[0]  = a0.x; r[1]  = a0.y; r[2]  = a0.z; r[3]  = a0.w;
                        r[4]  = a1.x; r[5]  = a1.y; r[6]  = a1.z; r[7]  = a1.w;
                        r[8]  = a2.x; r[9]  = a2.y; r[10] = a2.z; r[11] = a2.w;
                        r[12] = a3.x; r[13] = a3.y; r[14] = a3.z; r[15] = a3.w;
                        r[16] = a4.x; r[17] = a4.y;
                    }
#pragma unroll
                    for (int dz = 0; dz < 3; ++dz) {
                        int rel = (i - 1) - dz;          // pp = i-1
                        if (rel >= 0 && rel <= 1) {      // compile-time
#pragma unroll
                            for (int dx = 0; dx < 3; ++dx) {
                                float wgt = wv[dz * 9 + dy * 3 + dx];
#pragma unroll
                                for (int j = 0; j < 16; ++j)
                                    acc[rel][j] += r[dx + j] * wgt;
                            }
                        }
                    }
                }
            }
        }

        // finalize zc = z0 + (i-3): rel 0 at phase 3, rel 1 at phase 4
        {
            int rel = i - 3;
            if (rel >= 0 && rel <= 1) {  // compile-time
                int zc = z0 + rel;
                float res[16];
#pragma unroll
                for (int j = 0; j < 16; ++j) {
                    float t = acc[rel][j];
                    if (f != 0) {
                        float a = fabsf(t) - lam;
                        t       = a > 0.f ? copysignf(a, t) : 0.f;
                    }
                    res[j]      = t * sc;
                    acc[rel][j] = 0.f;
                }
                float* op = t0 + ((long)cc << 15) + (zc << 10) + cty * 32 + cx0i;
#pragma unroll
                for (int q = 0; q < 4; ++q)
                    *(float4*)(op + q * 4) = float4{res[q * 4], res[q * 4 + 1],
                                                    res[q * 4 + 2], res[q * 4 + 3]};
            }
        }

        if (sv) {
            // consume prefetch (arrived during fold), DWT, write buf i&1
            float v0[8], v1[8];
#pragma unroll
            for (int z = 0; z < 2; ++z)
#pragma unroll
                for (int yy = 0; yy < 2; ++yy) {
                    float4 q = pre[z * 2 + yy];
                    v0[z * 4 + yy * 2]     = q.x;
                    v0[z * 4 + yy * 2 + 1] = q.y;
                    v1[z * 4 + yy * 2]     = q.z;
                    v1[z * 4 + yy * 2 + 1] = q.w;
                }
            float o0[8], o1[8];
            haar_fwd(v0, o0);
            haar_fwd(v1, o1);
#pragma unroll
            for (int k = 0; k < 8; ++k) {
                pl[i & 1][k][y][xx + 1] = o0[k];
                pl[i & 1][k][y][xx + 2] = o1[k];
            }
            if (i == 1) {  // plane z0: stash raw LL for level-1 DWT
                llq00 = o0[0];
                llq01 = o1[0];
            }
            if (i == 2) {  // plane z0+1: complete level-1 cell, write cx1
                float l10 = o0[0], l11 = o1[0];
                float p00 = __shfl_xor(llq00, 16);
                float p01 = __shfl_xor(llq01, 16);
                float p10 = __shfl_xor(l10, 16);
                float p11 = __shfl_xor(l11, 16);
                int yp = (tid >> 4) & 1;  // y parity
                float v[8];
                if (yp == 0) {
                    v[0] = llq00; v[1] = llq01; v[2] = p00; v[3] = p01;
                    v[4] = l10;   v[5] = l11;   v[6] = p10; v[7] = p11;
                } else {
                    v[0] = p00;   v[1] = p01;   v[2] = llq00; v[3] = llq01;
                    v[4] = p10;   v[5] = p11;   v[6] = l10;   v[7] = l11;
                }
                float o[8];
                haar_fwd(v, o);
                int d  = z0 >> 1;
                int hy = (tid >> 4) >> 1;
                int wx = tid & 15;
                int sA = (d * 16 + hy) * 16 + wx;
                int f0 = yp * 4;
#pragma unroll
                for (int q = 0; q < 4; ++q)
                    cx1[((c * 8 + f0 + q) << 12) + sA] = o[f0 + q];
            }
        }
        __syncthreads();
    }
}

// ===================== Level-1 conv kernel (R10 form) =====================
template <int S, int SLOT>
__device__ __forceinline__ void load_plane4(const float* __restrict__ ip,
                                            int z, int ty, int x0,
                                            float win[4][3][6]) {
    bool zok = ((unsigned)z < (unsigned)S);
    const float* pp = ip + z * S * S;
#pragma unroll
    for (int dy = 0; dy < 3; ++dy) {
        int yy  = ty - 1 + dy;
        bool yok = zok && ((unsigned)yy < (unsigned)S);
        const float* rp = pp + yy * S;
        win[SLOT][dy][0] = (yok && x0 > 0) ? rp[x0 - 1] : 0.f;
        float4 m = yok ? *(const float4*)(rp + x0) : float4{0.f, 0.f, 0.f, 0.f};
        win[SLOT][dy][1] = m.x;
        win[SLOT][dy][2] = m.y;
        win[SLOT][dy][3] = m.z;
        win[SLOT][dy][4] = m.w;
        win[SLOT][dy][5] = (yok && (x0 + 4 < S)) ? rp[x0 + 4] : 0.f;
    }
}

template <int S, int SP, int SC, int SN>
__device__ __forceinline__ void conv_compute(int zo, int ty, int x0,
                                             const float* __restrict__ wv,
                                             const float win[4][3][6], float lam,
                                             float sc, bool hf,
                                             float* __restrict__ op) {
    float acc[4] = {0.f, 0.f, 0.f, 0.f};
#pragma unroll
    for (int dy = 0; dy < 3; ++dy)
#pragma unroll
        for (int dx = 0; dx < 3; ++dx) {
            float w0 = wv[0 * 9 + dy * 3 + dx];
            float w1 = wv[1 * 9 + dy * 3 + dx];
            float w2 = wv[2 * 9 + dy * 3 + dx];
#pragma unroll
            for (int j = 0; j < 4; ++j) {
                acc[j] += win[SP][dy][dx + j] * w0;  // static first index
                acc[j] += win[SC][dy][dx + j] * w1;
                acc[j] += win[SN][dy][dx + j] * w2;
            }
        }
    float4 r;
    float* rr = (float*)&r;
#pragma unroll
    for (int j = 0; j < 4; ++j) {
        float t = acc[j];
        if (hf) {
            float a = fabsf(t) - lam;
            t       = a > 0.f ? copysignf(a, t) : 0.f;
        }
        rr[j] = t * sc;
    }
    *(float4*)(op + (zo * S + ty) * S + x0) = r;
}

// 2-plane chunks -> grid 1024 (4 blocks/CU), all 4 plane-loads issued before
// any compute; cx1 L2-resident so the 2x plane re-read is ~free. XCD swizzle.
template <int S, int CPB>
__global__ __launch_bounds__(256) void dwconv_soft_pipe_k(
    const float* __restrict__ in, const float* __restrict__ wt,
    const float* __restrict__ wscale, const float* __restrict__ lambd_p,
    float* __restrict__ out) {
    constexpr int TX = S / 4;
    int bxl = ((blockIdx.x & 7) << 7) + (blockIdx.x >> 3);  // XCD-chunked, 1024
    int tid = threadIdx.x;
    int tx  = tid % TX;
    int ty  = (tid / TX) % S;
    int cs  = tid / (TX * S);
    int zc  = bxl & 7;   // 8 z-chunks of 2
    int cg  = bxl >> 3;  // 128 channel groups
    int cc  = cg * CPB + cs;
    const float* ip = in + (long)cc * (S * S * S);
    float* op       = out + (long)cc * (S * S * S);
    float wv[27];
#pragma unroll
    for (int k = 0; k < 27; ++k) wv[k] = wt[cc * 27 + k];
    float lam = *lambd_p;
    float sc  = wscale[cc];
    bool hf   = (cc & 7) != 0;
    int x0    = 4 * tx;
    int z0    = 2 * zc;  // slot of plane q = q & 3

    float win[4][3][6];
    if ((zc & 1) == 0) {  // z0 % 4 == 0
        load_plane4<S, 3>(ip, z0 - 1, ty, x0, win);
        load_plane4<S, 0>(ip, z0,     ty, x0, win);
        load_plane4<S, 1>(ip, z0 + 1, ty, x0, win);
        load_plane4<S, 2>(ip, z0 + 2, ty, x0, win);
        conv_compute<S, 3, 0, 1>(z0,     ty, x0, wv, win, lam, sc, hf, op);
        conv_compute<S, 0, 1, 2>(z0 + 1, ty, x0, wv, win, lam, sc, hf, op);
    } else {              // z0 % 4 == 2
        load_plane4<S, 1>(ip, z0 - 1, ty, x0, win);
        load_plane4<S, 2>(ip, z0,     ty, x0, win);
        load_plane4<S, 3>(ip, z0 + 1, ty, x0, win);
        load_plane4<S, 0>(ip, z0 + 2, ty, x0, win);
        conv_compute<S, 1, 2, 3>(z0,     ty, x0, wv, win, lam, sc, hf, op);
        conv_compute<S, 2, 3, 0>(z0 + 1, ty, x0, wv, win, lam, sc, hf, op);
    }
}

// ========== Final: LDS-tiled base conv + level-1 idwt + level-0 idwt =======
// FROZEN (R10 form): tile/mapping/epilogue-hoist/batched staging validated.
__global__ __launch_bounds__(256, 3) void final_k2(
    const float* __restrict__ x, const float* __restrict__ t0,
    const float* __restrict__ t1, const float* __restrict__ bw,
    const float* __restrict__ bb, const float* __restrict__ bscale,
    float* __restrict__ out) {
    __shared__ float xs[18 * 10 * 67];
    int bx = blockIdx.x;
    int c  = bx >> 5;
    int ti = bx & 31;
    int dt = ti >> 3;  // z tile (16 thick)
    int ht = ti & 7;   // y tile (8 thick)
    const float* xc = x + ((long)c << 18);

    int tid = threadIdx.x;
    int wc  = tid & 7;         // x chunk: cells w0..w0+3
    int hc  = (tid >> 3) & 3;  // h cell in tile
    int dc  = tid >> 5;        // d cell in tile
    int d   = dt * 8 + dc;
    int h   = ht * 4 + hc;
    int w0  = wc * 4;

    // ---- epilogue data: issue loads FIRST (independent of xs) ----
    int cell0 = (d << 10) + (h << 5) + w0;
    float4 t0v[8];
#pragma unroll
    for (int f = 0; f < 8; ++f)
        t0v[f] = *(const float4*)(t0 + (((long)(c * 8 + f)) << 15) + cell0);
    int s1b = ((d >> 1) * 16 + (h >> 1)) * 16 + (w0 >> 1);
    float2 t1v[8];
#pragma unroll
    for (int f = 0; f < 8; ++f)
        t1v[f] = *(const float2*)(t1 + ((c * 8 + f) << 12) + s1b);

    // ---- stage x tile: batched (5 loads in flight per batch) ----
    int zg0 = 16 * dt - 1, yg0 = 8 * ht - 1;
    constexpr int TOT = 18 * 10 * 66;  // 11880
#pragma unroll 1
    for (int k = 0; k < 10; ++k) {
        float v[5];
        int off[5];
#pragma unroll
        for (int b = 0; b < 5; ++b) {
            int i  = tid + (k * 5 + b) * 256;
            v[b]   = 0.f;
            off[b] = -1;
            if (i < TOT) {
                int pz = i / 660;
                int r  = i - pz * 660;
                int py = r / 66;
                int px = r - py * 66;
                int zg = zg0 + pz, yg = yg0 + py, xg = px - 1;
                bool ok = ((unsigned)zg < 64u) && ((unsigned)yg < 64u) &&
                          ((unsigned)xg < 64u);
                if (ok) v[b] = xc[(zg << 12) + (yg << 6) + xg];
                off[b] = (pz * 10 + py) * 67 + px;
            }
        }
#pragma unroll
        for (int b = 0; b < 5; ++b)
            if (off[b] >= 0) xs[off[b]] = v[b];
    }
    const float* wp0 = bw + c * 27;
    float wv[27];
#pragma unroll
    for (int k = 0; k < 27; ++k) wv[k] = wp0[k];
    float bias = bb[c], scl = bscale[c];
    __syncthreads();

    float acc[2][2][8];
#pragma unroll
    for (int oz = 0; oz < 2; ++oz)
#pragma unroll
        for (int oy = 0; oy < 2; ++oy)
#pragma unroll
            for (int m = 0; m < 8; ++m) acc[oz][oy][m] = 0.f;

#pragma unroll
    for (int pz = 0; pz < 4; ++pz) {
        float r[4][10];
#pragma unroll
        for (int py = 0; py < 4; ++py)
#pragma unroll
            for (int k = 0; k < 10; ++k)
                r[py][k] = xs[((2 * dc + pz) * 10 + (2 * hc + py)) * 67 + 8 * wc + k];
#pragma unroll
        for (int oz = 0; oz < 2; ++oz) {
            int kz = pz - oz;
            if (kz >= 0 && kz <= 2) {
#pragma unroll
                for (int py = 0; py < 4; ++py)
#pragma unroll
                    for (int oy = 0; oy < 2; ++oy) {
                        int ky = py - oy;
                        if (ky >= 0 && ky <= 2) {
#pragma unroll
                            for (int kx = 0; kx < 3; ++kx) {
                                float wgt = wv[kz * 9 + ky * 3 + kx];
#pragma unroll
                                for (int m = 0; m < 8; ++m)
                                    acc[oz][oy][m] += r[py][m + kx] * wgt;
                            }
                        }
                    }
            }
        }
    }

    // epilogue: t0/t1 already in registers; idwt + store
#pragma unroll
    for (int j = 0; j < 4; ++j) {
        int w = w0 + j;
        float tf[8];
#pragma unroll
        for (int f = 0; f < 8; ++f) tf[f] = ((const float*)&t0v[f])[j];
        float add = 0.f;
#pragma unroll
        for (int f = 0; f < 8; ++f) {
            float v  = (j >> 1) ? t1v[f].y : t1v[f].x;
            float sg = 1.f;
            if ((f & 4) && (d & 1)) sg = -sg;
            if ((f & 2) && (h & 1)) sg = -sg;
            if ((f & 1) && (j & 1)) sg = -sg;
            add += sg * v;
        }
        tf[0] += add * SQ3F;
        float contrib[8];
        haar_inv(tf, contrib);
#pragma unroll
        for (int oz = 0; oz < 2; ++oz)
#pragma unroll
            for (int oy = 0; oy < 2; ++oy) {
                float2 rr;
                rr.x = (acc[oz][oy][2 * j] + bias) * scl + contrib[oz * 4 + oy * 2];
                rr.y = (acc[oz][oy][2 * j + 1] + bias) * scl +
                       contrib[oz * 4 + oy * 2 + 1];
                *(float2*)(out + ((long)c << 18) + ((2 * d + oz) << 12) +
                           ((2 * h + oy) << 6) + 2 * w) = rr;
            }
    }
}

extern "C" void kernel_launch(void* const* d_in, const int* in_sizes, int n_in,
                              void* d_out, int out_size, void* d_ws, size_t ws_size,
                              hipStream_t stream) {
    const float* x      = (const float*)d_in[0];
    const float* base_w = (const float*)d_in[1];
    const float* base_b = (const float*)d_in[2];
    const float* base_s = (const float*)d_in[3];
    const float* w0     = (const float*)d_in[4];
    const float* w1     = (const float*)d_in[5];
    const float* ws0    = (const float*)d_in[6];
    const float* ws1    = (const float*)d_in[7];
    const float* lambd  = (const float*)d_in[8];
    float* out = (float*)d_out;

    // Workspace (floats): t0 16.8M | cx1 2.1M | t1 2.1M
    float* t0  = (float*)d_ws;
    float* cx1 = t0 + 16777216;
    float* t1  = cx1 + 2097152;

    // Level 0 fused: x -> t0 (conv+soft+scale, all 8 bands) + level-1 DWT cx1
    fused_l0_k<<<1024, 512, 0, stream>>>(x, w0, ws0, lambd, t0, cx1);
    // Level 1 conv+soft (2-plane chunks, 1024 blocks)
    dwconv_soft_pipe_k<16, 4><<<1024, 256, 0, stream>>>(cx1, w1, ws1, lambd, t1);
    // Final: base conv + level-1 idwt (fused) + level-0 idwt
    final_k2<<<2048, 256, 0, stream>>>(x, t0, t1, base_w, base_b, base_s, out);
}